// Round 4
// baseline (332.591 us; speedup 1.0000x reference)
//
#include <hip/hip_runtime.h>

// B=2, S=2048, IN_F=1024, HEADS=8, DPH=64, OUT_F=1024.
// Quirk: reshape is a raw view -> per (b,h) the Q/K/V matrices are CONTIGUOUS
// [2048,64] slabs of the [4096,512] projection output at offset bh*131072.
// Quirk: no pre-softmax scale; divide by 8 AFTER softmax (folded into combine).
//
// Attention: swapped operands (S^T = mfma(K,Q), O^T = mfma(V,P)) so softmax is
// per-lane + 2 shfl; K-SPLIT across gridDim.z (flash-decoding) for occupancy,
// f32 partials + (m,l) combined by k_comb.

using short8  = __attribute__((ext_vector_type(8))) short;
using short4v = __attribute__((ext_vector_type(4))) short;
using f32x4   = __attribute__((ext_vector_type(4))) float;
using float4v = __attribute__((ext_vector_type(4))) float;
using uint4v  = __attribute__((ext_vector_type(4))) unsigned int;

__device__ __forceinline__ unsigned short f2bf(float x) {
  unsigned int u = __float_as_uint(x);
  u += 0x7FFFu + ((u >> 16) & 1u);          // round-to-nearest-even
  return (unsigned short)(u >> 16);
}

#define GLD_LDS16(g, s)                                                              \
  __builtin_amdgcn_global_load_lds((const __attribute__((address_space(1))) unsigned int*)(g), \
                                   (__attribute__((address_space(3))) unsigned int*)(s), 16, 0, 0)

// ---------------- f32 -> bf16 convert (4 elems/thread) ----------------
__global__ __launch_bounds__(256) void k_cvt(const float* __restrict__ in,
                                             unsigned short* __restrict__ out,
                                             int n4) {
  int id = blockIdx.x * 256 + threadIdx.x;
  if (id >= n4) return;
  float4v v = *(const float4v*)(in + (size_t)id * 4);
  short4v o;
#pragma unroll
  for (int i = 0; i < 4; ++i) o[i] = (short)f2bf(v[i]);
  *(short4v*)(out + (size_t)id * 4) = o;
}

// ---- {Wq,Wk,Wv}[1024,512] f32 -> WT[3][512][1024] bf16, LDS-tiled ----
__global__ __launch_bounds__(256) void k_twt3(const float* __restrict__ Wq,
                                              const float* __restrict__ Wk,
                                              const float* __restrict__ Wv,
                                              unsigned short* __restrict__ WT) {
  __shared__ alignas(16) unsigned short t[64][72];
  const int z = blockIdx.z;
  const float* W = (z == 0) ? Wq : (z == 1) ? Wk : Wv;
  unsigned short* dst0 = WT + (size_t)z * 524288;
  const int k0 = blockIdx.x * 64, n0 = blockIdx.y * 64;
  const int kk = threadIdx.x & 63, g = (threadIdx.x >> 6) * 16;
  const float* src = W + (size_t)(k0 + kk) * 512 + n0 + g;
#pragma unroll
  for (int j4 = 0; j4 < 4; ++j4) {
    float4v v = *(const float4v*)(src + j4 * 4);
#pragma unroll
    for (int i = 0; i < 4; ++i) t[g + j4 * 4 + i][kk] = f2bf(v[i]);
  }
  __syncthreads();
  const int nn = threadIdx.x >> 2, kg = (threadIdx.x & 3) * 16;
  short8 o0, o1;
#pragma unroll
  for (int j = 0; j < 8; ++j) { o0[j] = t[nn][kg + j]; o1[j] = t[nn][kg + 8 + j]; }
  unsigned short* dst = dst0 + (size_t)(n0 + nn) * 1024 + k0 + kg;
  *(short8*)dst = o0;
  *(short8*)(dst + 8) = o1;
}

// ---- Wo[64,1024] f32 -> WoT[1024,64] bf16 ----
__global__ __launch_bounds__(256) void k_twtO(const float* __restrict__ W,
                                              unsigned short* __restrict__ WT) {
  __shared__ alignas(16) unsigned short t[64][72];
  const int n0 = blockIdx.y * 64;
  const int kk = threadIdx.x & 63, g = (threadIdx.x >> 6) * 16;
  const float* src = W + (size_t)kk * 1024 + n0 + g;
#pragma unroll
  for (int j4 = 0; j4 < 4; ++j4) {
    float4v v = *(const float4v*)(src + j4 * 4);
#pragma unroll
    for (int i = 0; i < 4; ++i) t[g + j4 * 4 + i][kk] = f2bf(v[i]);
  }
  __syncthreads();
  const int nn = threadIdx.x >> 2, kg = (threadIdx.x & 3) * 16;
  short8 o0, o1;
#pragma unroll
  for (int j = 0; j < 8; ++j) { o0[j] = t[nn][kg + j]; o1[j] = t[nn][kg + 8 + j]; }
  unsigned short* dst = WT + (size_t)(n0 + nn) * 64 + kg;
  *(short8*)dst = o0;
  *(short8*)(dst + 8) = o1;
}

// -------- V slab [2048,64] -> k-tiled VT[bh][k/64][64 d][64 k] --------
__global__ __launch_bounds__(256) void k_tv(const unsigned short* __restrict__ Vb,
                                            unsigned short* __restrict__ VT) {
  __shared__ alignas(16) unsigned short t[64][72];
  const int bh = blockIdx.y, r0 = blockIdx.x * 64;
  const int rr = threadIdx.x & 63, g = (threadIdx.x >> 6) * 16;
  const unsigned short* src = Vb + (size_t)bh * 131072 + (size_t)(r0 + rr) * 64 + g;
  short8 a = *(const short8*)src;
  short8 b = *(const short8*)(src + 8);
#pragma unroll
  for (int j = 0; j < 8; ++j) { t[g + j][rr] = a[j]; t[g + 8 + j][rr] = b[j]; }
  __syncthreads();
  const int d = threadIdx.x >> 2, rg = (threadIdx.x & 3) * 16;
  short8 o0, o1;
#pragma unroll
  for (int j = 0; j < 8; ++j) { o0[j] = t[d][rg + j]; o1[j] = t[d][rg + 8 + j]; }
  // tile = r0>>6 (r0 is 64-aligned); within-tile: d*64 + (rg..rg+15)
  unsigned short* dst = VT + (size_t)bh * 131072 + (size_t)(r0 >> 6) * 4096 + d * 64 + rg;
  *(short8*)dst = o0;
  *(short8*)(dst + 8) = o1;
}

// ------- fused QKV GEMM, 128x128 tile, 2-phase double-buffered LDS -------
__global__ __launch_bounds__(256) void k_gemmqkv(const unsigned short* __restrict__ A,
                                                 const unsigned short* __restrict__ WT,
                                                 unsigned short* __restrict__ Q,
                                                 unsigned short* __restrict__ K_,
                                                 unsigned short* __restrict__ V_) {
  __shared__ alignas(16) unsigned short As[2][128 * 64];   // 2 x 16 KB
  __shared__ alignas(16) unsigned short Bs[2][128 * 64];
  const int tid = threadIdx.x, w = tid >> 6, l = tid & 63;
  const int lr = l & 15, lg = l >> 4;
  const int m0 = blockIdx.x * 128, n0 = blockIdx.y * 128;
  const int wr = w >> 1, wc = w & 1;
  f32x4 acc[4][4] = {};
  const int srow = w * 8 + (l >> 3);
  const int scol = (l & 7) * 8;
  const unsigned short* ga = A  + (size_t)(m0 + srow) * 1024 + scol;
  const unsigned short* gb = WT + (size_t)(n0 + srow) * 1024 + scol;

#pragma unroll
  for (int i = 0; i < 4; ++i) {            // stage tile 0
    GLD_LDS16(ga + (size_t)i * 32768, &As[0][(i * 32 + w * 8) * 64]);
    GLD_LDS16(gb + (size_t)i * 32768, &Bs[0][(i * 32 + w * 8) * 64]);
  }
  asm volatile("s_waitcnt vmcnt(0)" ::: "memory");
  __syncthreads();

  int cur = 0;
  for (int kt = 0; kt < 16; ++kt) {
    if (kt < 15) {                          // stage next tile into cur^1
      const int k0 = (kt + 1) * 64;
#pragma unroll
      for (int i = 0; i < 4; ++i) {
        GLD_LDS16(ga + (size_t)i * 32768 + k0, &As[cur ^ 1][(i * 32 + w * 8) * 64]);
        GLD_LDS16(gb + (size_t)i * 32768 + k0, &Bs[cur ^ 1][(i * 32 + w * 8) * 64]);
      }
    }
#pragma unroll
    for (int kk = 0; kk < 2; ++kk) {
      short8 a[4], b[4];
#pragma unroll
      for (int mi = 0; mi < 4; ++mi)
        a[mi] = *(const short8*)&As[cur][(wr * 64 + mi * 16 + lr) * 64 + kk * 32 + lg * 8];
#pragma unroll
      for (int ni = 0; ni < 4; ++ni)
        b[ni] = *(const short8*)&Bs[cur][(wc * 64 + ni * 16 + lr) * 64 + kk * 32 + lg * 8];
#pragma unroll
      for (int mi = 0; mi < 4; ++mi)
#pragma unroll
        for (int ni = 0; ni < 4; ++ni)
          acc[mi][ni] = __builtin_amdgcn_mfma_f32_16x16x32_bf16(a[mi], b[ni], acc[mi][ni], 0, 0, 0);
    }
    asm volatile("s_waitcnt vmcnt(0)" ::: "memory");
    __syncthreads();
    cur ^= 1;
  }
  const int which = blockIdx.y >> 2;
  unsigned short* C = (which == 0) ? Q : (which == 1) ? K_ : V_;
  const int cbase = (blockIdx.y & 3) * 128 + wc * 64;
#pragma unroll
  for (int mi = 0; mi < 4; ++mi)
#pragma unroll
    for (int ni = 0; ni < 4; ++ni) {
      int row = m0 + wr * 64 + mi * 16 + lg * 4;
      int col = cbase + ni * 16 + lr;
#pragma unroll
      for (int r = 0; r < 4; ++r)
        C[(size_t)(row + r) * 512 + col] = f2bf(acc[mi][ni][r]);
    }
}

// ---------------- flash attention with K-split (gridDim.z partitions) ----------------
__global__ __launch_bounds__(256) void k_attn(const unsigned short* __restrict__ Qb,
                                              const unsigned short* __restrict__ Kb,
                                              const unsigned short* __restrict__ VT,
                                              float* __restrict__ Opart,
                                              float* __restrict__ ML) {
  __shared__ alignas(16) unsigned short Plds[4][16][72];
  const int tid = threadIdx.x, w = tid >> 6, l = tid & 63;
  const int lr = l & 15, lg = l >> 4;
  const int bh = blockIdx.y, sp = blockIdx.z;
  const int iters = 32 / gridDim.z;
  const int it0 = sp * iters;
  const int qrow = blockIdx.x * 64 + w * 16;
  const unsigned short* Qh  = Qb + (size_t)bh * 131072;
  const unsigned short* Kh  = Kb + (size_t)bh * 131072;

  short8 qb0 = *(const short8*)&Qh[(size_t)(qrow + lr) * 64 + lg * 8];
  short8 qb1 = *(const short8*)&Qh[(size_t)(qrow + lr) * 64 + 32 + lg * 8];

  f32x4 O[4] = {};
  float m_i = -1e30f, l_i = 0.f;

  // per-lane tile pointers; all loads are base + 13-bit imm, one bump per iter
  const unsigned short* kp  = Kh + ((size_t)(it0 * 64 + lr) * 64 + lg * 8);
  const unsigned short* kp2 = kp + 2048;                       // rows +32
  const unsigned short* vp  = VT + (size_t)bh * 131072 + (size_t)it0 * 4096 + (size_t)lr * 64 + lg * 8;
  const unsigned short* vp2 = vp + 2048;                       // d-rows +32

  short8 kr[8];
#pragma unroll
  for (int t = 0; t < 2; ++t) {
    kr[t * 2]     = *(const short8*)(kp  + t * 1024);
    kr[t * 2 + 1] = *(const short8*)(kp  + t * 1024 + 32);
    kr[t * 2 + 4] = *(const short8*)(kp2 + t * 1024);
    kr[t * 2 + 5] = *(const short8*)(kp2 + t * 1024 + 32);
  }

  for (int it = 0; it < iters; ++it) {
    // V A-fragments issued early (consumed after softmax); f-major imm offsets
    short8 vr[8];
#pragma unroll
    for (int f = 0; f < 2; ++f) {
      vr[f * 2]     = *(const short8*)(vp  + f * 1024);
      vr[f * 2 + 1] = *(const short8*)(vp  + f * 1024 + 32);
      vr[f * 2 + 4] = *(const short8*)(vp2 + f * 1024);
      vr[f * 2 + 5] = *(const short8*)(vp2 + f * 1024 + 32);
    }
    // S^T tile
    f32x4 s[4] = {};
#pragma unroll
    for (int t = 0; t < 4; ++t) {
      s[t] = __builtin_amdgcn_mfma_f32_16x16x32_bf16(kr[t * 2],     qb0, s[t], 0, 0, 0);
      s[t] = __builtin_amdgcn_mfma_f32_16x16x32_bf16(kr[t * 2 + 1], qb1, s[t], 0, 0, 0);
    }
    // prefetch next K-tile
    const unsigned short* kpn  = (it < iters - 1) ? kp + 4096 : kp;
    const unsigned short* kpn2 = kpn + 2048;
    short8 kn[8];
#pragma unroll
    for (int t = 0; t < 2; ++t) {
      kn[t * 2]     = *(const short8*)(kpn  + t * 1024);
      kn[t * 2 + 1] = *(const short8*)(kpn  + t * 1024 + 32);
      kn[t * 2 + 4] = *(const short8*)(kpn2 + t * 1024);
      kn[t * 2 + 5] = *(const short8*)(kpn2 + t * 1024 + 32);
    }
    // softmax: in-lane over 16 + 2 shfl
    float t0 = fmaxf(fmaxf(s[0][0], s[0][1]), fmaxf(s[0][2], s[0][3]));
    float t1 = fmaxf(fmaxf(s[1][0], s[1][1]), fmaxf(s[1][2], s[1][3]));
    float t2 = fmaxf(fmaxf(s[2][0], s[2][1]), fmaxf(s[2][2], s[2][3]));
    float t3 = fmaxf(fmaxf(s[3][0], s[3][1]), fmaxf(s[3][2], s[3][3]));
    float tmax = fmaxf(fmaxf(t0, t1), fmaxf(t2, t3));
    tmax = fmaxf(tmax, __shfl_xor(tmax, 16));
    tmax = fmaxf(tmax, __shfl_xor(tmax, 32));
    float mnew  = fmaxf(m_i, tmax);
    float alpha = __expf(m_i - mnew);
    float p[4][4];
#pragma unroll
    for (int t = 0; t < 4; ++t)
#pragma unroll
      for (int r = 0; r < 4; ++r) p[t][r] = __expf(s[t][r] - mnew);
    float u0 = (p[0][0] + p[0][1]) + (p[0][2] + p[0][3]);
    float u1 = (p[1][0] + p[1][1]) + (p[1][2] + p[1][3]);
    float u2 = (p[2][0] + p[2][1]) + (p[2][2] + p[2][3]);
    float u3 = (p[3][0] + p[3][1]) + (p[3][2] + p[3][3]);
    float ls = (u0 + u1) + (u2 + u3);
    ls += __shfl_xor(ls, 16);
    ls += __shfl_xor(ls, 32);
    l_i = l_i * alpha + ls;
    m_i = mnew;
#pragma unroll
    for (int f = 0; f < 4; ++f) O[f] *= alpha;
    // P -> wave-local LDS bounce into B-fragment layout
#pragma unroll
    for (int t = 0; t < 4; ++t) {
      short4v pk;
#pragma unroll
      for (int r = 0; r < 4; ++r) pk[r] = (short)f2bf(p[t][r]);
      *(short4v*)&Plds[w][lr][t * 16 + lg * 4] = pk;
    }
    asm volatile("s_waitcnt lgkmcnt(0)" ::: "memory");
    __builtin_amdgcn_sched_barrier(0);
    short8 pb0 = *(const short8*)&Plds[w][lr][lg * 8];
    short8 pb1 = *(const short8*)&Plds[w][lr][32 + lg * 8];
#pragma unroll
    for (int f = 0; f < 4; ++f) {
      O[f] = __builtin_amdgcn_mfma_f32_16x16x32_bf16(vr[f * 2],     pb0, O[f], 0, 0, 0);
      O[f] = __builtin_amdgcn_mfma_f32_16x16x32_bf16(vr[f * 2 + 1], pb1, O[f], 0, 0, 0);
    }
#pragma unroll
    for (int i = 0; i < 8; ++i) kr[i] = kn[i];
    kp += 4096; kp2 += 4096; vp += 4096; vp2 += 4096;
  }
  // partial epilogue: raw O^T (f32) + per-q (m,l)
  const size_t q = (size_t)sp * 32768 + bh * 2048 + qrow + lr;
  float* obase = Opart + q * 64;
#pragma unroll
  for (int f = 0; f < 4; ++f)
    *(float4v*)(obase + f * 16 + lg * 4) = O[f];
  if (lg == 0) {
    float* mlp = ML + q * 2;
    mlp[0] = m_i; mlp[1] = l_i;
  }
}

// ---------------- combine K-split partials -> ctx bf16 ----------------
template <int NS>
__global__ __launch_bounds__(256) void k_comb(const float* __restrict__ Opart,
                                              const float* __restrict__ ML,
                                              unsigned short* __restrict__ ctx) {
  int id = blockIdx.x * 256 + threadIdx.x;       // 524288 = 32768 q x 16 d4-chunks
  int q = id >> 4, d4 = (id & 15) * 4;
  float mv[NS], lv[NS];
  float M = -1e30f;
#pragma unroll
  for (int s = 0; s < NS; ++s) {
    const float* mlp = ML + ((size_t)s * 32768 + q) * 2;
    mv[s] = mlp[0]; lv[s] = mlp[1];
    M = fmaxf(M, mv[s]);
  }
  float L = 0.f, wgt[NS];
#pragma unroll
  for (int s = 0; s < NS; ++s) { wgt[s] = __expf(mv[s] - M); L += wgt[s] * lv[s]; }
  f32x4 o = {};
#pragma unroll
  for (int s = 0; s < NS; ++s) {
    float4v po = *(const float4v*)(Opart + ((size_t)s * 32768 + q) * 64 + d4);
#pragma unroll
    for (int r = 0; r < 4; ++r) o[r] += wgt[s] * po[r];
  }
  float sc = 0.125f / L;
  short4v pk;
#pragma unroll
  for (int r = 0; r < 4; ++r) pk[r] = (short)f2bf(o[r] * sc);
  *(short4v*)(ctx + (size_t)q * 64 + d4) = pk;
}

// ------- out projection, 128x128 tile: OUT[32768,1024] f32 = ctx @ WoT^T + bo -------
__global__ __launch_bounds__(256) void k_gemmo(const unsigned short* __restrict__ A,
                                               const unsigned short* __restrict__ BT,
                                               const float* __restrict__ bias,
                                               float* __restrict__ C) {
  __shared__ alignas(16) unsigned short As[128 * 64];
  __shared__ alignas(16) unsigned short Bs[128 * 64];
  const int tid = threadIdx.x, w = tid >> 6, l = tid & 63;
  const int lr = l & 15, lg = l >> 4;
  const int m0 = blockIdx.x * 128, n0 = blockIdx.y * 128;
  const int wr = w >> 1, wc = w & 1;
  const int srow = w * 8 + (l >> 3);
  const int scol = (l & 7) * 8;
  const unsigned short* ga = A  + (size_t)(m0 + srow) * 64 + scol;
  const unsigned short* gb = BT + (size_t)(n0 + srow) * 64 + scol;
#pragma unroll
  for (int i = 0; i < 4; ++i) {
    GLD_LDS16(ga + (size_t)i * 2048, As + (i * 32 + w * 8) * 64);
    GLD_LDS16(gb + (size_t)i * 2048, Bs + (i * 32 + w * 8) * 64);
  }
  asm volatile("s_waitcnt vmcnt(0)" ::: "memory");
  __syncthreads();
  f32x4 acc[4][4] = {};
#pragma unroll
  for (int kk = 0; kk < 2; ++kk) {
    short8 a[4], b[4];
#pragma unroll
    for (int mi = 0; mi < 4; ++mi)
      a[mi] = *(const short8*)&As[(wr * 64 + mi * 16 + lr) * 64 + kk * 32 + lg * 8];
#pragma unroll
    for (int ni = 0; ni < 4; ++ni)
      b[ni] = *(const short8*)&Bs[(wc * 64 + ni * 16 + lr) * 64 + kk * 32 + lg * 8];
#pragma unroll
    for (int mi = 0; mi < 4; ++mi)
#pragma unroll
      for (int ni = 0; ni < 4; ++ni)
        acc[mi][ni] = __builtin_amdgcn_mfma_f32_16x16x32_bf16(a[mi], b[ni], acc[mi][ni], 0, 0, 0);
  }
  float bv[4];
#pragma unroll
  for (int ni = 0; ni < 4; ++ni) bv[ni] = bias[n0 + wc * 64 + ni * 16 + lr];
#pragma unroll
  for (int mi = 0; mi < 4; ++mi)
#pragma unroll
    for (int ni = 0; ni < 4; ++ni) {
      int row = m0 + wr * 64 + mi * 16 + lg * 4;
      int col = n0 + wc * 64 + ni * 16 + lr;
#pragma unroll
      for (int r = 0; r < 4; ++r)
        C[(size_t)(row + r) * 1024 + col] = acc[mi][ni][r] + bv[ni];
    }
}

extern "C" void kernel_launch(void* const* d_in, const int* in_sizes, int n_in,
                              void* d_out, int out_size, void* d_ws, size_t ws_size,
                              hipStream_t stream) {
  const float* X  = (const float*)d_in[0];
  const float* Wq = (const float*)d_in[1];
  const float* Wk = (const float*)d_in[2];
  const float* Wv = (const float*)d_in[3];
  const float* Wo = (const float*)d_in[4];
  const float* bo = (const float*)d_in[5];
  float* out = (float*)d_out;

  char* ws = (char*)d_ws;
  unsigned short* Xb    = (unsigned short*)ws; ws += 8388608;   // [4096,1024] bf16
  unsigned short* WqkvT = (unsigned short*)ws; ws += 3145728;   // [3][512][1024]
  unsigned short* WoT   = (unsigned short*)ws; ws += 131072;    // [1024,64]
  unsigned short* Qb    = (unsigned short*)ws; ws += 4194304;   // [4096,512]
  unsigned short* Kb    = (unsigned short*)ws; ws += 4194304;
  unsigned short* Vb    = (unsigned short*)ws; ws += 4194304;
  unsigned short* VT    = (unsigned short*)ws; ws += 4194304;   // [16][32][64][64] k-tiled
  unsigned short* Cx    = (unsigned short*)ws; ws += 4194304;   // [32768,64]
  size_t base = (size_t)(ws - (char*)d_ws);

  // choose K-split by available workspace (constant per process -> graph-safe)
  int nsplit = 4;
  if (base + 4 * (8388608ULL + 262144ULL) > ws_size) nsplit = 2;
  if (base + 2 * (8388608ULL + 262144ULL) > ws_size) nsplit = 1;
  float* Opart = (float*)ws; ws += (size_t)nsplit * 8388608;    // [ns][32768][64] f32
  float* ML    = (float*)ws; ws += (size_t)nsplit * 262144;     // [ns][32768][2] f32

  k_cvt<<<4096, 256, 0, stream>>>(X, Xb, 1048576);
  k_twt3<<<dim3(16, 8, 3), 256, 0, stream>>>(Wq, Wk, Wv, WqkvT);
  k_twtO<<<dim3(1, 16), 256, 0, stream>>>(Wo, WoT);

  k_gemmqkv<<<dim3(32, 12), 256, 0, stream>>>(Xb, WqkvT, Qb, Kb, Vb);

  k_tv<<<dim3(32, 16), 256, 0, stream>>>(Vb, VT);
  k_attn<<<dim3(32, 16, nsplit), 256, 0, stream>>>(Qb, Kb, VT, Opart, ML);
  if (nsplit == 4)      k_comb<4><<<2048, 256, 0, stream>>>(Opart, ML, Cx);
  else if (nsplit == 2) k_comb<2><<<2048, 256, 0, stream>>>(Opart, ML, Cx);
  else                  k_comb<1><<<2048, 256, 0, stream>>>(Opart, ML, Cx);

  k_gemmo<<<dim3(256, 8), 256, 0, stream>>>(Cx, WoT, bo, out);
}

// Round 5
// 240.526 us; speedup vs baseline: 1.3828x; 1.3828x over previous
//
#include <hip/hip_runtime.h>

// B=2, S=2048, IN_F=1024, HEADS=8, DPH=64, OUT_F=1024.
// Quirk: raw-view reshape -> per (b,h) Q/K/V are CONTIGUOUS [2048,64] slabs.
// Quirk: no pre-softmax scale; /8 applied post-softmax (folded into combine).
//
// k_attn: 4 waves x 32 q-rows; K/V tiles staged once per block into LDS
// (double-buffered, XOR-swizzled via pre-swizzled global source), swapped-
// operand MFMA so softmax is per-lane; K-split z=2 + f32 partial combine.

using short8  = __attribute__((ext_vector_type(8))) short;
using short4v = __attribute__((ext_vector_type(4))) short;
using f32x4   = __attribute__((ext_vector_type(4))) float;
using float4v = __attribute__((ext_vector_type(4))) float;
using uint4v  = __attribute__((ext_vector_type(4))) unsigned int;

__device__ __forceinline__ unsigned short f2bf(float x) {
  unsigned int u = __float_as_uint(x);
  u += 0x7FFFu + ((u >> 16) & 1u);
  return (unsigned short)(u >> 16);
}

#define GLD_LDS16(g, s)                                                              \
  __builtin_amdgcn_global_load_lds((const __attribute__((address_space(1))) unsigned int*)(g), \
                                   (__attribute__((address_space(3))) unsigned int*)(s), 16, 0, 0)

// ---------------- f32 -> bf16 convert ----------------
__global__ __launch_bounds__(256) void k_cvt(const float* __restrict__ in,
                                             unsigned short* __restrict__ out,
                                             int n4) {
  int id = blockIdx.x * 256 + threadIdx.x;
  if (id >= n4) return;
  float4v v = *(const float4v*)(in + (size_t)id * 4);
  short4v o;
#pragma unroll
  for (int i = 0; i < 4; ++i) o[i] = (short)f2bf(v[i]);
  *(short4v*)(out + (size_t)id * 4) = o;
}

// ---- {Wq,Wk,Wv}[1024,512] f32 -> WT[3][512][1024] bf16 ----
__global__ __launch_bounds__(256) void k_twt3(const float* __restrict__ Wq,
                                              const float* __restrict__ Wk,
                                              const float* __restrict__ Wv,
                                              unsigned short* __restrict__ WT) {
  __shared__ alignas(16) unsigned short t[64][72];
  const int z = blockIdx.z;
  const float* W = (z == 0) ? Wq : (z == 1) ? Wk : Wv;
  unsigned short* dst0 = WT + (size_t)z * 524288;
  const int k0 = blockIdx.x * 64, n0 = blockIdx.y * 64;
  const int kk = threadIdx.x & 63, g = (threadIdx.x >> 6) * 16;
  const float* src = W + (size_t)(k0 + kk) * 512 + n0 + g;
#pragma unroll
  for (int j4 = 0; j4 < 4; ++j4) {
    float4v v = *(const float4v*)(src + j4 * 4);
#pragma unroll
    for (int i = 0; i < 4; ++i) t[g + j4 * 4 + i][kk] = f2bf(v[i]);
  }
  __syncthreads();
  const int nn = threadIdx.x >> 2, kg = (threadIdx.x & 3) * 16;
  short8 o0, o1;
#pragma unroll
  for (int j = 0; j < 8; ++j) { o0[j] = t[nn][kg + j]; o1[j] = t[nn][kg + 8 + j]; }
  unsigned short* dst = dst0 + (size_t)(n0 + nn) * 1024 + k0 + kg;
  *(short8*)dst = o0;
  *(short8*)(dst + 8) = o1;
}

// ---- Wo[64,1024] f32 -> WoT[1024,64] bf16 ----
__global__ __launch_bounds__(256) void k_twtO(const float* __restrict__ W,
                                              unsigned short* __restrict__ WT) {
  __shared__ alignas(16) unsigned short t[64][72];
  const int n0 = blockIdx.y * 64;
  const int kk = threadIdx.x & 63, g = (threadIdx.x >> 6) * 16;
  const float* src = W + (size_t)kk * 1024 + n0 + g;
#pragma unroll
  for (int j4 = 0; j4 < 4; ++j4) {
    float4v v = *(const float4v*)(src + j4 * 4);
#pragma unroll
    for (int i = 0; i < 4; ++i) t[g + j4 * 4 + i][kk] = f2bf(v[i]);
  }
  __syncthreads();
  const int nn = threadIdx.x >> 2, kg = (threadIdx.x & 3) * 16;
  short8 o0, o1;
#pragma unroll
  for (int j = 0; j < 8; ++j) { o0[j] = t[nn][kg + j]; o1[j] = t[nn][kg + 8 + j]; }
  unsigned short* dst = WT + (size_t)(n0 + nn) * 64 + kg;
  *(short8*)dst = o0;
  *(short8*)(dst + 8) = o1;
}

// -------- V slab [2048,64] -> k-tiled VT[bh][k/64][64 d][64 k] --------
__global__ __launch_bounds__(256) void k_tv(const unsigned short* __restrict__ Vb,
                                            unsigned short* __restrict__ VT) {
  __shared__ alignas(16) unsigned short t[64][72];
  const int bh = blockIdx.y, r0 = blockIdx.x * 64;
  const int rr = threadIdx.x & 63, g = (threadIdx.x >> 6) * 16;
  const unsigned short* src = Vb + (size_t)bh * 131072 + (size_t)(r0 + rr) * 64 + g;
  short8 a = *(const short8*)src;
  short8 b = *(const short8*)(src + 8);
#pragma unroll
  for (int j = 0; j < 8; ++j) { t[g + j][rr] = a[j]; t[g + 8 + j][rr] = b[j]; }
  __syncthreads();
  const int d = threadIdx.x >> 2, rg = (threadIdx.x & 3) * 16;
  short8 o0, o1;
#pragma unroll
  for (int j = 0; j < 8; ++j) { o0[j] = t[d][rg + j]; o1[j] = t[d][rg + 8 + j]; }
  unsigned short* dst = VT + (size_t)bh * 131072 + (size_t)(r0 >> 6) * 4096 + d * 64 + rg;
  *(short8*)dst = o0;
  *(short8*)(dst + 8) = o1;
}

// ------- fused QKV GEMM: tile 64Mx128N, dbuf LDS, 768 blocks (3/CU) -------
__global__ __launch_bounds__(256) void k_gemmqkv(const unsigned short* __restrict__ A,
                                                 const unsigned short* __restrict__ WT,
                                                 unsigned short* __restrict__ Q,
                                                 unsigned short* __restrict__ K_,
                                                 unsigned short* __restrict__ V_) {
  __shared__ alignas(16) unsigned short As[2][4096];    // [buf][64r x 64k]
  __shared__ alignas(16) unsigned short Bs[2][8192];    // [buf][128r x 64k]
  const int tid = threadIdx.x, w = tid >> 6, l = tid & 63;
  const int lr = l & 15, lg = l >> 4;
  const int m0 = blockIdx.x * 64;
  const int yy = blockIdx.y;                            // 0..11 -> B rows yy*128
  const int wr = w >> 1, wc = w & 1;
  const unsigned short* ga = A  + (size_t)(m0 + w * 16 + (l >> 3)) * 1024 + (l & 7) * 8;
  const unsigned short* gb = WT + (size_t)(yy * 128 + w * 32 + (l >> 3)) * 1024 + (l & 7) * 8;

#pragma unroll
  for (int n = 0; n < 2; ++n) GLD_LDS16(ga + n * 8192, &As[0][w * 1024 + n * 512]);
#pragma unroll
  for (int n = 0; n < 4; ++n) GLD_LDS16(gb + n * 8192, &Bs[0][w * 2048 + n * 512]);
  asm volatile("s_waitcnt vmcnt(0)" ::: "memory");
  __syncthreads();

  f32x4 acc[2][4] = {};
  int cur = 0;
  for (int kt = 0; kt < 16; ++kt) {
    if (kt < 15) {
      const int k0 = (kt + 1) * 64;
#pragma unroll
      for (int n = 0; n < 2; ++n) GLD_LDS16(ga + n * 8192 + k0, &As[cur ^ 1][w * 1024 + n * 512]);
#pragma unroll
      for (int n = 0; n < 4; ++n) GLD_LDS16(gb + n * 8192 + k0, &Bs[cur ^ 1][w * 2048 + n * 512]);
    }
#pragma unroll
    for (int kk = 0; kk < 2; ++kk) {
      short8 a[2], b[4];
#pragma unroll
      for (int mi = 0; mi < 2; ++mi)
        a[mi] = *(const short8*)&As[cur][(wr * 32 + mi * 16 + lr) * 64 + kk * 32 + lg * 8];
#pragma unroll
      for (int ni = 0; ni < 4; ++ni)
        b[ni] = *(const short8*)&Bs[cur][(wc * 64 + ni * 16 + lr) * 64 + kk * 32 + lg * 8];
#pragma unroll
      for (int mi = 0; mi < 2; ++mi)
#pragma unroll
        for (int ni = 0; ni < 4; ++ni)
          acc[mi][ni] = __builtin_amdgcn_mfma_f32_16x16x32_bf16(a[mi], b[ni], acc[mi][ni], 0, 0, 0);
    }
    asm volatile("s_waitcnt vmcnt(0)" ::: "memory");
    __syncthreads();
    cur ^= 1;
  }
  const int which = yy >> 2;
  unsigned short* C = (which == 0) ? Q : (which == 1) ? K_ : V_;
  const int cbase = (yy & 3) * 128 + wc * 64;
#pragma unroll
  for (int mi = 0; mi < 2; ++mi)
#pragma unroll
    for (int ni = 0; ni < 4; ++ni) {
      int row = m0 + wr * 32 + mi * 16 + lg * 4;
      int col = cbase + ni * 16 + lr;
#pragma unroll
      for (int r = 0; r < 4; ++r)
        C[(size_t)(row + r) * 512 + col] = f2bf(acc[mi][ni][r]);
    }
}

// ---------------- flash attention: LDS-staged K/V shared by 4 waves ----------------
__global__ __launch_bounds__(256) void k_attn(const unsigned short* __restrict__ Qb,
                                              const unsigned short* __restrict__ Kb,
                                              const unsigned short* __restrict__ VT,
                                              float* __restrict__ Opart,
                                              float* __restrict__ ML) {
  __shared__ alignas(16) unsigned short Ks[2][4096];    // [buf][64k x 64d] swizzled
  __shared__ alignas(16) unsigned short Vs[2][4096];    // [buf][64d x 64k] swizzled
  __shared__ alignas(16) unsigned short Plds[4][32][72];
  const int tid = threadIdx.x, w = tid >> 6, l = tid & 63;
  const int lr = l & 15, lg = l >> 4;
  const int bh = blockIdx.y, sp = blockIdx.z;
  const int iters = 32 / gridDim.z;
  const int it0 = sp * iters;
  const int q0 = blockIdx.x * 128;
  const unsigned short* Qh  = Qb + (size_t)bh * 131072;
  const unsigned short* Kh  = Kb + (size_t)bh * 131072;
  const unsigned short* VTh = VT + (size_t)bh * 131072;

  // staging: per lane source with inverse-swizzled column; LDS dest linear.
  // lane covers row w*16 + n*8 + (l>>3), 16B chunk (l&7); stored chunk c holds
  // logical chunk c ^ (row&7)  ->  src chunk = (l&7) ^ ((l>>3)&7).
  const int srow = w * 16 + (l >> 3);
  const int scol = (((l & 7) ^ ((l >> 3) & 7)) << 3);
  const unsigned short* kps = Kh  + (size_t)it0 * 4096 + srow * 64 + scol;
  const unsigned short* vps = VTh + (size_t)it0 * 4096 + srow * 64 + scol;

#define STAGE_KV(buf, trel)                                                   \
  {                                                                           \
    const unsigned short* ks_ = kps + (size_t)(trel) * 4096;                  \
    const unsigned short* vs_ = vps + (size_t)(trel) * 4096;                  \
    GLD_LDS16(ks_,       &Ks[buf][w * 1024]);                                 \
    GLD_LDS16(ks_ + 512, &Ks[buf][w * 1024 + 512]);                           \
    GLD_LDS16(vs_,       &Vs[buf][w * 1024]);                                 \
    GLD_LDS16(vs_ + 512, &Vs[buf][w * 1024 + 512]);                           \
  }

  // Q fragments: wave owns 32 q-rows (2 groups of 16)
  short8 qf[2][2];
#pragma unroll
  for (int qg = 0; qg < 2; ++qg) {
    const unsigned short* qrow = &Qh[(size_t)(q0 + w * 32 + qg * 16 + lr) * 64 + lg * 8];
    qf[qg][0] = *(const short8*)qrow;
    qf[qg][1] = *(const short8*)(qrow + 32);
  }

  f32x4 O[4][2] = {};
  float m_i[2] = {-1e30f, -1e30f}, l_i[2] = {0.f, 0.f};

  STAGE_KV(0, 0);
  asm volatile("s_waitcnt vmcnt(0)" ::: "memory");
  __syncthreads();

  const int fcol = ((lg ^ (lr & 7)) << 3);   // swizzled loc of logical chunk lg
  int cur = 0;
  for (int it = 0; it < iters; ++it) {
    if (it < iters - 1) STAGE_KV(cur ^ 1, it + 1);
    // ---- S^T = K @ Q^T ----
    f32x4 s[4][2] = {};
#pragma unroll
    for (int t = 0; t < 4; ++t) {
      const unsigned short* kRow = &Ks[cur][(t * 16 + lr) * 64];
      short8 ka = *(const short8*)(kRow + fcol);
      short8 kc = *(const short8*)(kRow + (fcol ^ 32));
      s[t][0] = __builtin_amdgcn_mfma_f32_16x16x32_bf16(ka, qf[0][0], s[t][0], 0, 0, 0);
      s[t][0] = __builtin_amdgcn_mfma_f32_16x16x32_bf16(kc, qf[0][1], s[t][0], 0, 0, 0);
      s[t][1] = __builtin_amdgcn_mfma_f32_16x16x32_bf16(ka, qf[1][0], s[t][1], 0, 0, 0);
      s[t][1] = __builtin_amdgcn_mfma_f32_16x16x32_bf16(kc, qf[1][1], s[t][1], 0, 0, 0);
    }
    // ---- V fragments (ready in Vs[cur]) ----
    short8 vf[4][2];
#pragma unroll
    for (int f = 0; f < 4; ++f) {
      const unsigned short* vRow = &Vs[cur][(f * 16 + lr) * 64];
      vf[f][0] = *(const short8*)(vRow + fcol);
      vf[f][1] = *(const short8*)(vRow + (fcol ^ 32));
    }
    // ---- online softmax per q-group (per-lane q = qg*16+lr... col=lr) ----
#pragma unroll
    for (int qg = 0; qg < 2; ++qg) {
      float t0 = fmaxf(fmaxf(s[0][qg][0], s[0][qg][1]), fmaxf(s[0][qg][2], s[0][qg][3]));
      float t1 = fmaxf(fmaxf(s[1][qg][0], s[1][qg][1]), fmaxf(s[1][qg][2], s[1][qg][3]));
      float t2 = fmaxf(fmaxf(s[2][qg][0], s[2][qg][1]), fmaxf(s[2][qg][2], s[2][qg][3]));
      float t3 = fmaxf(fmaxf(s[3][qg][0], s[3][qg][1]), fmaxf(s[3][qg][2], s[3][qg][3]));
      float tmax = fmaxf(fmaxf(t0, t1), fmaxf(t2, t3));
      tmax = fmaxf(tmax, __shfl_xor(tmax, 16));
      tmax = fmaxf(tmax, __shfl_xor(tmax, 32));
      float mnew  = fmaxf(m_i[qg], tmax);
      float alpha = __expf(m_i[qg] - mnew);
      float p[4][4];
#pragma unroll
      for (int t = 0; t < 4; ++t)
#pragma unroll
        for (int r = 0; r < 4; ++r) p[t][r] = __expf(s[t][qg][r] - mnew);
      float u0 = (p[0][0] + p[0][1]) + (p[0][2] + p[0][3]);
      float u1 = (p[1][0] + p[1][1]) + (p[1][2] + p[1][3]);
      float u2 = (p[2][0] + p[2][1]) + (p[2][2] + p[2][3]);
      float u3 = (p[3][0] + p[3][1]) + (p[3][2] + p[3][3]);
      float ls = (u0 + u1) + (u2 + u3);
      ls += __shfl_xor(ls, 16);
      ls += __shfl_xor(ls, 32);
      l_i[qg] = l_i[qg] * alpha + ls;
      m_i[qg] = mnew;
#pragma unroll
      for (int f = 0; f < 4; ++f) O[f][qg] *= alpha;
#pragma unroll
      for (int t = 0; t < 4; ++t) {
        short4v pk;
#pragma unroll
        for (int r = 0; r < 4; ++r) pk[r] = (short)f2bf(p[t][r]);
        *(short4v*)&Plds[w][qg * 16 + lr][t * 16 + lg * 4] = pk;
      }
    }
    asm volatile("s_waitcnt lgkmcnt(0)" ::: "memory");
    __builtin_amdgcn_sched_barrier(0);
#pragma unroll
    for (int qg = 0; qg < 2; ++qg) {
      short8 pb0 = *(const short8*)&Plds[w][qg * 16 + lr][lg * 8];
      short8 pb1 = *(const short8*)&Plds[w][qg * 16 + lr][32 + lg * 8];
#pragma unroll
      for (int f = 0; f < 4; ++f) {
        O[f][qg] = __builtin_amdgcn_mfma_f32_16x16x32_bf16(vf[f][0], pb0, O[f][qg], 0, 0, 0);
        O[f][qg] = __builtin_amdgcn_mfma_f32_16x16x32_bf16(vf[f][1], pb1, O[f][qg], 0, 0, 0);
      }
    }
    asm volatile("s_waitcnt vmcnt(0)" ::: "memory");
    __syncthreads();
    cur ^= 1;
  }
  // partial epilogue: raw O^T f32 + (m,l)
#pragma unroll
  for (int qg = 0; qg < 2; ++qg) {
    const size_t q = (size_t)sp * 32768 + bh * 2048 + q0 + w * 32 + qg * 16 + lr;
    float* obase = Opart + q * 64;
#pragma unroll
    for (int f = 0; f < 4; ++f)
      *(float4v*)(obase + f * 16 + lg * 4) = O[f][qg];
    if (lg == 0) {
      float* mlp = ML + q * 2;
      mlp[0] = m_i[qg]; mlp[1] = l_i[qg];
    }
  }
}

// ---------------- combine K-split partials -> ctx bf16 ----------------
template <int NS>
__global__ __launch_bounds__(256) void k_comb(const float* __restrict__ Opart,
                                              const float* __restrict__ ML,
                                              unsigned short* __restrict__ ctx) {
  int id = blockIdx.x * 256 + threadIdx.x;
  int q = id >> 4, d4 = (id & 15) * 4;
  float mv[NS], lv[NS];
  float M = -1e30f;
#pragma unroll
  for (int s = 0; s < NS; ++s) {
    const float* mlp = ML + ((size_t)s * 32768 + q) * 2;
    mv[s] = mlp[0]; lv[s] = mlp[1];
    M = fmaxf(M, mv[s]);
  }
  float L = 0.f, wgt[NS];
#pragma unroll
  for (int s = 0; s < NS; ++s) { wgt[s] = __expf(mv[s] - M); L += wgt[s] * lv[s]; }
  f32x4 o = {};
#pragma unroll
  for (int s = 0; s < NS; ++s) {
    float4v po = *(const float4v*)(Opart + ((size_t)s * 32768 + q) * 64 + d4);
#pragma unroll
    for (int r = 0; r < 4; ++r) o[r] += wgt[s] * po[r];
  }
  float sc = 0.125f / L;
  short4v pk;
#pragma unroll
  for (int r = 0; r < 4; ++r) pk[r] = (short)f2bf(o[r] * sc);
  *(short4v*)(ctx + (size_t)q * 64 + d4) = pk;
}

// ------- out projection: OUT[32768,1024] f32 = ctx @ WoT^T + bo -------
__global__ __launch_bounds__(256) void k_gemmo(const unsigned short* __restrict__ A,
                                               const unsigned short* __restrict__ BT,
                                               const float* __restrict__ bias,
                                               float* __restrict__ C) {
  __shared__ alignas(16) unsigned short As[128 * 64];
  __shared__ alignas(16) unsigned short Bs[128 * 64];
  const int tid = threadIdx.x, w = tid >> 6, l = tid & 63;
  const int lr = l & 15, lg = l >> 4;
  const int m0 = blockIdx.x * 128, n0 = blockIdx.y * 128;
  const int wr = w >> 1, wc = w & 1;
  const int srow = w * 8 + (l >> 3);
  const int scol = (l & 7) * 8;
  const unsigned short* ga = A  + (size_t)(m0 + srow) * 64 + scol;
  const unsigned short* gb = BT + (size_t)(n0 + srow) * 64 + scol;
#pragma unroll
  for (int i = 0; i < 4; ++i) {
    GLD_LDS16(ga + (size_t)i * 2048, As + (i * 32 + w * 8) * 64);
    GLD_LDS16(gb + (size_t)i * 2048, Bs + (i * 32 + w * 8) * 64);
  }
  asm volatile("s_waitcnt vmcnt(0)" ::: "memory");
  __syncthreads();
  f32x4 acc[4][4] = {};
#pragma unroll
  for (int kk = 0; kk < 2; ++kk) {
    short8 a[4], b[4];
#pragma unroll
    for (int mi = 0; mi < 4; ++mi)
      a[mi] = *(const short8*)&As[(wr * 64 + mi * 16 + lr) * 64 + kk * 32 + lg * 8];
#pragma unroll
    for (int ni = 0; ni < 4; ++ni)
      b[ni] = *(const short8*)&Bs[(wc * 64 + ni * 16 + lr) * 64 + kk * 32 + lg * 8];
#pragma unroll
    for (int mi = 0; mi < 4; ++mi)
#pragma unroll
      for (int ni = 0; ni < 4; ++ni)
        acc[mi][ni] = __builtin_amdgcn_mfma_f32_16x16x32_bf16(a[mi], b[ni], acc[mi][ni], 0, 0, 0);
  }
  float bv[4];
#pragma unroll
  for (int ni = 0; ni < 4; ++ni) bv[ni] = bias[n0 + wc * 64 + ni * 16 + lr];
#pragma unroll
  for (int mi = 0; mi < 4; ++mi)
#pragma unroll
    for (int ni = 0; ni < 4; ++ni) {
      int row = m0 + wr * 64 + mi * 16 + lg * 4;
      int col = n0 + wc * 64 + ni * 16 + lr;
#pragma unroll
      for (int r = 0; r < 4; ++r)
        C[(size_t)(row + r) * 1024 + col] = acc[mi][ni][r] + bv[ni];
    }
}

extern "C" void kernel_launch(void* const* d_in, const int* in_sizes, int n_in,
                              void* d_out, int out_size, void* d_ws, size_t ws_size,
                              hipStream_t stream) {
  const float* X  = (const float*)d_in[0];
  const float* Wq = (const float*)d_in[1];
  const float* Wk = (const float*)d_in[2];
  const float* Wv = (const float*)d_in[3];
  const float* Wo = (const float*)d_in[4];
  const float* bo = (const float*)d_in[5];
  float* out = (float*)d_out;

  char* ws = (char*)d_ws;
  unsigned short* Xb    = (unsigned short*)ws; ws += 8388608;   // [4096,1024] bf16
  unsigned short* WqkvT = (unsigned short*)ws; ws += 3145728;   // [3][512][1024]
  unsigned short* WoT   = (unsigned short*)ws; ws += 131072;    // [1024,64]
  unsigned short* Qb    = (unsigned short*)ws; ws += 4194304;   // [4096,512]
  unsigned short* Kb    = (unsigned short*)ws; ws += 4194304;
  unsigned short* Vb    = (unsigned short*)ws; ws += 4194304;
  unsigned short* VT    = (unsigned short*)ws; ws += 4194304;   // [16][32][64][64] k-tiled
  unsigned short* Cx    = (unsigned short*)ws; ws += 4194304;   // [32768,64]
  size_t base = (size_t)(ws - (char*)d_ws);

  int nsplit = 2;
  if (base + 2 * (8388608ULL + 262144ULL) > ws_size) nsplit = 1;
  float* Opart = (float*)ws; ws += (size_t)nsplit * 8388608;    // [ns][32768][64] f32
  float* ML    = (float*)ws; ws += (size_t)nsplit * 262144;     // [ns][32768][2] f32

  k_cvt<<<4096, 256, 0, stream>>>(X, Xb, 1048576);
  k_twt3<<<dim3(16, 8, 3), 256, 0, stream>>>(Wq, Wk, Wv, WqkvT);
  k_twtO<<<dim3(1, 16), 256, 0, stream>>>(Wo, WoT);

  k_gemmqkv<<<dim3(64, 12), 256, 0, stream>>>(Xb, WqkvT, Qb, Kb, Vb);

  k_tv<<<dim3(32, 16), 256, 0, stream>>>(Vb, VT);
  k_attn<<<dim3(16, 16, nsplit), 256, 0, stream>>>(Qb, Kb, VT, Opart, ML);
  if (nsplit == 2) k_comb<2><<<2048, 256, 0, stream>>>(Opart, ML, Cx);
  else             k_comb<1><<<2048, 256, 0, stream>>>(Opart, ML, Cx);

  k_gemmo<<<dim3(256, 8), 256, 0, stream>>>(Cx, WoT, bo, out);
}

// Round 6
// 231.748 us; speedup vs baseline: 1.4351x; 1.0379x over previous
//
#include <hip/hip_runtime.h>

// B=2, S=2048, IN_F=1024, HEADS=8, DPH=64, OUT_F=1024.
// Quirk: raw-view reshape -> per (b,h) Q/K/V are CONTIGUOUS [2048,64] slabs.
// Quirk: no pre-softmax scale; /8 applied post-softmax (folded into epilogue).
//
// k_attn: 8 waves x 16 q-rows, KBLK=128 (2 subtiles) per phase, K/V staged in
// LDS (dbuf, XOR-swizzled via pre-swizzled global source), swapped-operand
// MFMA (per-lane softmax), swizzled LDS P-bounce, XCD-aware head mapping.

using short8  = __attribute__((ext_vector_type(8))) short;
using short4v = __attribute__((ext_vector_type(4))) short;
using f32x4   = __attribute__((ext_vector_type(4))) float;
using float4v = __attribute__((ext_vector_type(4))) float;
using uint4v  = __attribute__((ext_vector_type(4))) unsigned int;

__device__ __forceinline__ unsigned short f2bf(float x) {
  unsigned int u = __float_as_uint(x);
  u += 0x7FFFu + ((u >> 16) & 1u);
  return (unsigned short)(u >> 16);
}

#define GLD_LDS16(g, s)                                                              \
  __builtin_amdgcn_global_load_lds((const __attribute__((address_space(1))) unsigned int*)(g), \
                                   (__attribute__((address_space(3))) unsigned int*)(s), 16, 0, 0)

// ---------------- f32 -> bf16 convert ----------------
__global__ __launch_bounds__(256) void k_cvt(const float* __restrict__ in,
                                             unsigned short* __restrict__ out,
                                             int n4) {
  int id = blockIdx.x * 256 + threadIdx.x;
  if (id >= n4) return;
  float4v v = *(const float4v*)(in + (size_t)id * 4);
  short4v o;
#pragma unroll
  for (int i = 0; i < 4; ++i) o[i] = (short)f2bf(v[i]);
  *(short4v*)(out + (size_t)id * 4) = o;
}

// ---- {Wq,Wk,Wv}[1024,512] f32 -> WT[3][512][1024] bf16 ----
__global__ __launch_bounds__(256) void k_twt3(const float* __restrict__ Wq,
                                              const float* __restrict__ Wk,
                                              const float* __restrict__ Wv,
                                              unsigned short* __restrict__ WT) {
  __shared__ alignas(16) unsigned short t[64][72];
  const int z = blockIdx.z;
  const float* W = (z == 0) ? Wq : (z == 1) ? Wk : Wv;
  unsigned short* dst0 = WT + (size_t)z * 524288;
  const int k0 = blockIdx.x * 64, n0 = blockIdx.y * 64;
  const int kk = threadIdx.x & 63, g = (threadIdx.x >> 6) * 16;
  const float* src = W + (size_t)(k0 + kk) * 512 + n0 + g;
#pragma unroll
  for (int j4 = 0; j4 < 4; ++j4) {
    float4v v = *(const float4v*)(src + j4 * 4);
#pragma unroll
    for (int i = 0; i < 4; ++i) t[g + j4 * 4 + i][kk] = f2bf(v[i]);
  }
  __syncthreads();
  const int nn = threadIdx.x >> 2, kg = (threadIdx.x & 3) * 16;
  short8 o0, o1;
#pragma unroll
  for (int j = 0; j < 8; ++j) { o0[j] = t[nn][kg + j]; o1[j] = t[nn][kg + 8 + j]; }
  unsigned short* dst = dst0 + (size_t)(n0 + nn) * 1024 + k0 + kg;
  *(short8*)dst = o0;
  *(short8*)(dst + 8) = o1;
}

// ---- Wo[64,1024] f32 -> WoT[1024,64] bf16 ----
__global__ __launch_bounds__(256) void k_twtO(const float* __restrict__ W,
                                              unsigned short* __restrict__ WT) {
  __shared__ alignas(16) unsigned short t[64][72];
  const int n0 = blockIdx.y * 64;
  const int kk = threadIdx.x & 63, g = (threadIdx.x >> 6) * 16;
  const float* src = W + (size_t)kk * 1024 + n0 + g;
#pragma unroll
  for (int j4 = 0; j4 < 4; ++j4) {
    float4v v = *(const float4v*)(src + j4 * 4);
#pragma unroll
    for (int i = 0; i < 4; ++i) t[g + j4 * 4 + i][kk] = f2bf(v[i]);
  }
  __syncthreads();
  const int nn = threadIdx.x >> 2, kg = (threadIdx.x & 3) * 16;
  short8 o0, o1;
#pragma unroll
  for (int j = 0; j < 8; ++j) { o0[j] = t[nn][kg + j]; o1[j] = t[nn][kg + 8 + j]; }
  unsigned short* dst = WT + (size_t)(n0 + nn) * 64 + kg;
  *(short8*)dst = o0;
  *(short8*)(dst + 8) = o1;
}

// -------- V slab [2048,64] -> k-tiled VT[bh][k/64][64 d][64 k] --------
__global__ __launch_bounds__(256) void k_tv(const unsigned short* __restrict__ Vb,
                                            unsigned short* __restrict__ VT) {
  __shared__ alignas(16) unsigned short t[64][72];
  const int bh = blockIdx.y, r0 = blockIdx.x * 64;
  const int rr = threadIdx.x & 63, g = (threadIdx.x >> 6) * 16;
  const unsigned short* src = Vb + (size_t)bh * 131072 + (size_t)(r0 + rr) * 64 + g;
  short8 a = *(const short8*)src;
  short8 b = *(const short8*)(src + 8);
#pragma unroll
  for (int j = 0; j < 8; ++j) { t[g + j][rr] = a[j]; t[g + 8 + j][rr] = b[j]; }
  __syncthreads();
  const int d = threadIdx.x >> 2, rg = (threadIdx.x & 3) * 16;
  short8 o0, o1;
#pragma unroll
  for (int j = 0; j < 8; ++j) { o0[j] = t[d][rg + j]; o1[j] = t[d][rg + 8 + j]; }
  unsigned short* dst = VT + (size_t)bh * 131072 + (size_t)(r0 >> 6) * 4096 + d * 64 + rg;
  *(short8*)dst = o0;
  *(short8*)(dst + 8) = o1;
}

// ------- fused QKV GEMM: tile 64Mx128N, dbuf LDS, 768 blocks (3/CU) -------
__global__ __launch_bounds__(256) void k_gemmqkv(const unsigned short* __restrict__ A,
                                                 const unsigned short* __restrict__ WT,
                                                 unsigned short* __restrict__ Q,
                                                 unsigned short* __restrict__ K_,
                                                 unsigned short* __restrict__ V_) {
  __shared__ alignas(16) unsigned short As[2][4096];
  __shared__ alignas(16) unsigned short Bs[2][8192];
  const int tid = threadIdx.x, w = tid >> 6, l = tid & 63;
  const int lr = l & 15, lg = l >> 4;
  const int m0 = blockIdx.x * 64;
  const int yy = blockIdx.y;
  const int wr = w >> 1, wc = w & 1;
  const unsigned short* ga = A  + (size_t)(m0 + w * 16 + (l >> 3)) * 1024 + (l & 7) * 8;
  const unsigned short* gb = WT + (size_t)(yy * 128 + w * 32 + (l >> 3)) * 1024 + (l & 7) * 8;

#pragma unroll
  for (int n = 0; n < 2; ++n) GLD_LDS16(ga + n * 8192, &As[0][w * 1024 + n * 512]);
#pragma unroll
  for (int n = 0; n < 4; ++n) GLD_LDS16(gb + n * 8192, &Bs[0][w * 2048 + n * 512]);
  asm volatile("s_waitcnt vmcnt(0)" ::: "memory");
  __syncthreads();

  f32x4 acc[2][4] = {};
  int cur = 0;
  for (int kt = 0; kt < 16; ++kt) {
    if (kt < 15) {
      const int k0 = (kt + 1) * 64;
#pragma unroll
      for (int n = 0; n < 2; ++n) GLD_LDS16(ga + n * 8192 + k0, &As[cur ^ 1][w * 1024 + n * 512]);
#pragma unroll
      for (int n = 0; n < 4; ++n) GLD_LDS16(gb + n * 8192 + k0, &Bs[cur ^ 1][w * 2048 + n * 512]);
    }
#pragma unroll
    for (int kk = 0; kk < 2; ++kk) {
      short8 a[2], b[4];
#pragma unroll
      for (int mi = 0; mi < 2; ++mi)
        a[mi] = *(const short8*)&As[cur][(wr * 32 + mi * 16 + lr) * 64 + kk * 32 + lg * 8];
#pragma unroll
      for (int ni = 0; ni < 4; ++ni)
        b[ni] = *(const short8*)&Bs[cur][(wc * 64 + ni * 16 + lr) * 64 + kk * 32 + lg * 8];
#pragma unroll
      for (int mi = 0; mi < 2; ++mi)
#pragma unroll
        for (int ni = 0; ni < 4; ++ni)
          acc[mi][ni] = __builtin_amdgcn_mfma_f32_16x16x32_bf16(a[mi], b[ni], acc[mi][ni], 0, 0, 0);
    }
    asm volatile("s_waitcnt vmcnt(0)" ::: "memory");
    __syncthreads();
    cur ^= 1;
  }
  const int which = yy >> 2;
  unsigned short* C = (which == 0) ? Q : (which == 1) ? K_ : V_;
  const int cbase = (yy & 3) * 128 + wc * 64;
#pragma unroll
  for (int mi = 0; mi < 2; ++mi)
#pragma unroll
    for (int ni = 0; ni < 4; ++ni) {
      int row = m0 + wr * 32 + mi * 16 + lg * 4;
      int col = cbase + ni * 16 + lr;
#pragma unroll
      for (int r = 0; r < 4; ++r)
        C[(size_t)(row + r) * 512 + col] = f2bf(acc[mi][ni][r]);
    }
}

// ------- flash attention: 8 waves x 16 q, KBLK=128, LDS dbuf, XCD-mapped -------
__global__ __launch_bounds__(512) void k_attn(const unsigned short* __restrict__ Qb,
                                              const unsigned short* __restrict__ Kb,
                                              const unsigned short* __restrict__ VT,
                                              unsigned short* __restrict__ ctx) {
  __shared__ alignas(16) unsigned short Ks[2][8192];   // [buf][2 subtiles][64k x 64d] swz
  __shared__ alignas(16) unsigned short Vs[2][8192];   // [buf][2 subtiles][64d x 64k] swz
  __shared__ alignas(16) unsigned short Plds[8][16][128];  // per-wave, chunk-XOR swz
  const int tid = threadIdx.x, w = tid >> 6, l = tid & 63;
  const int lr = l & 15, lg = l >> 4;
  // XCD-aware mapping: assuming round-robin dispatch, XCD (bid&7) serves heads
  // {2*(bid&7), 2*(bid&7)+1} only -> K/V (1 MB) resident in its 4 MB L2.
  const int bid = blockIdx.x;
  const int xcd = bid & 7, j = bid >> 3;
  const int bh = xcd * 2 + (j >> 4);
  const int q0 = (j & 15) * 128;
  const int qrow = q0 + w * 16;
  const unsigned short* Qh  = Qb + (size_t)bh * 131072;
  const unsigned short* Kh  = Kb + (size_t)bh * 131072;
  const unsigned short* VTh = VT + (size_t)bh * 131072;

  short8 qb0 = *(const short8*)&Qh[(size_t)(qrow + lr) * 64 + lg * 8];
  short8 qb1 = *(const short8*)&Qh[(size_t)(qrow + lr) * 64 + 32 + lg * 8];

  // staging: wave w covers rows w*8..w*8+7 of each 64-row subtile; source column
  // inverse-swizzled so linear LDS + swizzled reads match (both-sides rule).
  const int srow = w * 8 + (l >> 3);
  const int scol = (((l & 7) ^ ((l >> 3) & 7)) << 3);
  const unsigned short* kps = Kh  + (size_t)srow * 64 + scol;
  const unsigned short* vps = VTh + (size_t)srow * 64 + scol;

#define STAGE(buf, it)                                                         \
  {                                                                            \
    _Pragma("unroll")                                                          \
    for (int sub = 0; sub < 2; ++sub) {                                        \
      GLD_LDS16(kps + (size_t)(2 * (it) + sub) * 4096, &Ks[buf][sub * 4096 + w * 512]); \
      GLD_LDS16(vps + (size_t)(2 * (it) + sub) * 4096, &Vs[buf][sub * 4096 + w * 512]); \
    }                                                                          \
  }

  f32x4 O[4] = {};
  float m_i = -1e30f, l_i = 0.f;

  STAGE(0, 0);
  asm volatile("s_waitcnt vmcnt(0)" ::: "memory");
  __syncthreads();

  const int fcol = ((lg ^ (lr & 7)) << 3);
  char* prow = (char*)&Plds[w][lr][0];
  int cur = 0;
  for (int it = 0; it < 16; ++it) {
    if (it < 15) STAGE(cur ^ 1, it + 1);
    // ---- S^T = K @ Q^T over 128 k ----
    f32x4 s[8] = {};
#pragma unroll
    for (int t = 0; t < 8; ++t) {
      const unsigned short* kRow = &Ks[cur][(t >> 2) * 4096 + ((t & 3) * 16 + lr) * 64];
      short8 ka = *(const short8*)(kRow + fcol);
      short8 kc = *(const short8*)(kRow + (fcol ^ 32));
      s[t] = __builtin_amdgcn_mfma_f32_16x16x32_bf16(ka, qb0, s[t], 0, 0, 0);
      s[t] = __builtin_amdgcn_mfma_f32_16x16x32_bf16(kc, qb1, s[t], 0, 0, 0);
    }
    // ---- V fragments (issued early; latency hidden under softmax) ----
    short8 vf[4][4];
#pragma unroll
    for (int f = 0; f < 4; ++f) {
      const char* vRow0 = (const char*)&Vs[cur][(f * 16 + lr) * 64];
#pragma unroll
      for (int ks = 0; ks < 4; ++ks) {
        int ch = (((ks & 1) * 4 + lg) ^ (lr & 7));
        vf[f][ks] = *(const short8*)(vRow0 + (ks >> 1) * 8192 + ch * 16);
      }
    }
    // ---- online softmax (per-lane q=lr; reduce across 4 lg-lanes) ----
    float tm[8];
#pragma unroll
    for (int t = 0; t < 8; ++t)
      tm[t] = fmaxf(fmaxf(s[t][0], s[t][1]), fmaxf(s[t][2], s[t][3]));
    float tmax = fmaxf(fmaxf(fmaxf(tm[0], tm[1]), fmaxf(tm[2], tm[3])),
                       fmaxf(fmaxf(tm[4], tm[5]), fmaxf(tm[6], tm[7])));
    tmax = fmaxf(tmax, __shfl_xor(tmax, 16));
    tmax = fmaxf(tmax, __shfl_xor(tmax, 32));
    float mnew  = fmaxf(m_i, tmax);
    float alpha = __expf(m_i - mnew);
    float p[8][4];
#pragma unroll
    for (int t = 0; t < 8; ++t)
#pragma unroll
      for (int r = 0; r < 4; ++r) p[t][r] = __expf(s[t][r] - mnew);
    float us[8];
#pragma unroll
    for (int t = 0; t < 8; ++t)
      us[t] = (p[t][0] + p[t][1]) + (p[t][2] + p[t][3]);
    float ls = ((us[0] + us[1]) + (us[2] + us[3])) + ((us[4] + us[5]) + (us[6] + us[7]));
    ls += __shfl_xor(ls, 16);
    ls += __shfl_xor(ls, 32);
    l_i = l_i * alpha + ls;
    m_i = mnew;
#pragma unroll
    for (int f = 0; f < 4; ++f) O[f] *= alpha;
    // ---- P -> swizzled per-wave LDS bounce ----
#pragma unroll
    for (int t = 0; t < 8; ++t) {
      short4v pk;
#pragma unroll
      for (int r = 0; r < 4; ++r) pk[r] = (short)f2bf(p[t][r]);
      int ch = ((2 * t + (lg >> 1)) ^ (lr & 7));
      *(short4v*)(prow + ch * 16 + (lg & 1) * 8) = pk;
    }
    asm volatile("s_waitcnt lgkmcnt(0)" ::: "memory");
    __builtin_amdgcn_sched_barrier(0);
    short8 pb[4];
#pragma unroll
    for (int ks = 0; ks < 4; ++ks)
      pb[ks] = *(const short8*)(prow + (((ks * 4 + lg) ^ (lr & 7)) << 4));
    // ---- O^T += V @ P ----
#pragma unroll
    for (int ks = 0; ks < 4; ++ks)
#pragma unroll
      for (int f = 0; f < 4; ++f)
        O[f] = __builtin_amdgcn_mfma_f32_16x16x32_bf16(vf[f][ks], pb[ks], O[f], 0, 0, 0);
    if (it < 15) {
      asm volatile("s_waitcnt vmcnt(0)" ::: "memory");
      __syncthreads();
    }
    cur ^= 1;
  }
  // epilogue: per-lane scale (post-softmax /8 + 1/l), packed b64 stores
  const float scale = 0.125f / l_i;
  unsigned short* base = ctx + (size_t)(bh * 2048 + qrow + lr) * 64;
#pragma unroll
  for (int f = 0; f < 4; ++f) {
    short4v o;
#pragma unroll
    for (int r = 0; r < 4; ++r) o[r] = (short)f2bf(O[f][r] * scale);
    *(short4v*)(base + f * 16 + lg * 4) = o;
  }
}

// ------- out projection: OUT[32768,1024] f32 = ctx @ WoT^T + bo -------
__global__ __launch_bounds__(256) void k_gemmo(const unsigned short* __restrict__ A,
                                               const unsigned short* __restrict__ BT,
                                               const float* __restrict__ bias,
                                               float* __restrict__ C) {
  __shared__ alignas(16) unsigned short As[128 * 64];
  __shared__ alignas(16) unsigned short Bs[128 * 64];
  const int tid = threadIdx.x, w = tid >> 6, l = tid & 63;
  const int lr = l & 15, lg = l >> 4;
  const int m0 = blockIdx.x * 128, n0 = blockIdx.y * 128;
  const int wr = w >> 1, wc = w & 1;
  const int srow = w * 8 + (l >> 3);
  const int scol = (l & 7) * 8;
  const unsigned short* ga = A  + (size_t)(m0 + srow) * 64 + scol;
  const unsigned short* gb = BT + (size_t)(n0 + srow) * 64 + scol;
#pragma unroll
  for (int i = 0; i < 4; ++i) {
    GLD_LDS16(ga + (size_t)i * 2048, As + (i * 32 + w * 8) * 64);
    GLD_LDS16(gb + (size_t)i * 2048, Bs + (i * 32 + w * 8) * 64);
  }
  asm volatile("s_waitcnt vmcnt(0)" ::: "memory");
  __syncthreads();
  f32x4 acc[4][4] = {};
#pragma unroll
  for (int kk = 0; kk < 2; ++kk) {
    short8 a[4], b[4];
#pragma unroll
    for (int mi = 0; mi < 4; ++mi)
      a[mi] = *(const short8*)&As[(wr * 64 + mi * 16 + lr) * 64 + kk * 32 + lg * 8];
#pragma unroll
    for (int ni = 0; ni < 4; ++ni)
      b[ni] = *(const short8*)&Bs[(wc * 64 + ni * 16 + lr) * 64 + kk * 32 + lg * 8];
#pragma unroll
    for (int mi = 0; mi < 4; ++mi)
#pragma unroll
      for (int ni = 0; ni < 4; ++ni)
        acc[mi][ni] = __builtin_amdgcn_mfma_f32_16x16x32_bf16(a[mi], b[ni], acc[mi][ni], 0, 0, 0);
  }
  float bv[4];
#pragma unroll
  for (int ni = 0; ni < 4; ++ni) bv[ni] = bias[n0 + wc * 64 + ni * 16 + lr];
#pragma unroll
  for (int mi = 0; mi < 4; ++mi)
#pragma unroll
    for (int ni = 0; ni < 4; ++ni) {
      int row = m0 + wr * 64 + mi * 16 + lg * 4;
      int col = n0 + wc * 64 + ni * 16 + lr;
#pragma unroll
      for (int r = 0; r < 4; ++r)
        C[(size_t)(row + r) * 1024 + col] = acc[mi][ni][r] + bv[ni];
    }
}

extern "C" void kernel_launch(void* const* d_in, const int* in_sizes, int n_in,
                              void* d_out, int out_size, void* d_ws, size_t ws_size,
                              hipStream_t stream) {
  const float* X  = (const float*)d_in[0];
  const float* Wq = (const float*)d_in[1];
  const float* Wk = (const float*)d_in[2];
  const float* Wv = (const float*)d_in[3];
  const float* Wo = (const float*)d_in[4];
  const float* bo = (const float*)d_in[5];
  float* out = (float*)d_out;

  char* ws = (char*)d_ws;
  unsigned short* Xb    = (unsigned short*)ws; ws += 8388608;   // [4096,1024] bf16
  unsigned short* WqkvT = (unsigned short*)ws; ws += 3145728;   // [3][512][1024]
  unsigned short* WoT   = (unsigned short*)ws; ws += 131072;    // [1024,64]
  unsigned short* Qb    = (unsigned short*)ws; ws += 4194304;   // [4096,512]
  unsigned short* Kb    = (unsigned short*)ws; ws += 4194304;
  unsigned short* Vb    = (unsigned short*)ws; ws += 4194304;
  unsigned short* VT    = (unsigned short*)ws; ws += 4194304;   // [16][32][64][64] k-tiled
  unsigned short* Cx    = (unsigned short*)ws; ws += 4194304;   // [32768,64]

  k_cvt<<<4096, 256, 0, stream>>>(X, Xb, 1048576);
  k_twt3<<<dim3(16, 8, 3), 256, 0, stream>>>(Wq, Wk, Wv, WqkvT);
  k_twtO<<<dim3(1, 16), 256, 0, stream>>>(Wo, WoT);

  k_gemmqkv<<<dim3(64, 12), 256, 0, stream>>>(Xb, WqkvT, Qb, Kb, Vb);

  k_tv<<<dim3(32, 16), 256, 0, stream>>>(Vb, VT);
  k_attn<<<256, 512, 0, stream>>>(Qb, Kb, VT, Cx);
  k_gemmo<<<dim3(256, 8), 256, 0, stream>>>(Cx, WoT, bo, out);
}

// Round 7
// 226.427 us; speedup vs baseline: 1.4689x; 1.0235x over previous
//
#include <hip/hip_runtime.h>

// B=2, S=2048, IN_F=1024, HEADS=8, DPH=64, OUT_F=1024.
// Quirk: raw-view reshape -> per (b,h) Q/K/V are CONTIGUOUS [2048,64] slabs.
// Quirk: no pre-softmax scale; /8 applied post-softmax (folded into epilogue).

using short8  = __attribute__((ext_vector_type(8))) short;
using short4v = __attribute__((ext_vector_type(4))) short;
using f32x4   = __attribute__((ext_vector_type(4))) float;
using float4v = __attribute__((ext_vector_type(4))) float;
using uint4v  = __attribute__((ext_vector_type(4))) unsigned int;

__device__ __forceinline__ unsigned short f2bf(float x) {
  unsigned int u = __float_as_uint(x);
  u += 0x7FFFu + ((u >> 16) & 1u);
  return (unsigned short)(u >> 16);
}

#define GLD_LDS16(g, s)                                                              \
  __builtin_amdgcn_global_load_lds((const __attribute__((address_space(1))) unsigned int*)(g), \
                                   (__attribute__((address_space(3))) unsigned int*)(s), 16, 0, 0)

// ---------------- f32 -> bf16 convert ----------------
__global__ __launch_bounds__(256) void k_cvt(const float* __restrict__ in,
                                             unsigned short* __restrict__ out,
                                             int n4) {
  int id = blockIdx.x * 256 + threadIdx.x;
  if (id >= n4) return;
  float4v v = *(const float4v*)(in + (size_t)id * 4);
  short4v o;
#pragma unroll
  for (int i = 0; i < 4; ++i) o[i] = (short)f2bf(v[i]);
  *(short4v*)(out + (size_t)id * 4) = o;
}

// ---- {Wq,Wk,Wv}[1024,512] f32 -> WT[3][512][1024] bf16 ----
__global__ __launch_bounds__(256) void k_twt3(const float* __restrict__ Wq,
                                              const float* __restrict__ Wk,
                                              const float* __restrict__ Wv,
                                              unsigned short* __restrict__ WT) {
  __shared__ alignas(16) unsigned short t[64][72];
  const int z = blockIdx.z;
  const float* W = (z == 0) ? Wq : (z == 1) ? Wk : Wv;
  unsigned short* dst0 = WT + (size_t)z * 524288;
  const int k0 = blockIdx.x * 64, n0 = blockIdx.y * 64;
  const int kk = threadIdx.x & 63, g = (threadIdx.x >> 6) * 16;
  const float* src = W + (size_t)(k0 + kk) * 512 + n0 + g;
#pragma unroll
  for (int j4 = 0; j4 < 4; ++j4) {
    float4v v = *(const float4v*)(src + j4 * 4);
#pragma unroll
    for (int i = 0; i < 4; ++i) t[g + j4 * 4 + i][kk] = f2bf(v[i]);
  }
  __syncthreads();
  const int nn = threadIdx.x >> 2, kg = (threadIdx.x & 3) * 16;
  short8 o0, o1;
#pragma unroll
  for (int j = 0; j < 8; ++j) { o0[j] = t[nn][kg + j]; o1[j] = t[nn][kg + 8 + j]; }
  unsigned short* dst = dst0 + (size_t)(n0 + nn) * 1024 + k0 + kg;
  *(short8*)dst = o0;
  *(short8*)(dst + 8) = o1;
}

// ---- Wo[64,1024] f32 -> WoT[1024,64] bf16 ----
__global__ __launch_bounds__(256) void k_twtO(const float* __restrict__ W,
                                              unsigned short* __restrict__ WT) {
  __shared__ alignas(16) unsigned short t[64][72];
  const int n0 = blockIdx.y * 64;
  const int kk = threadIdx.x & 63, g = (threadIdx.x >> 6) * 16;
  const float* src = W + (size_t)kk * 1024 + n0 + g;
#pragma unroll
  for (int j4 = 0; j4 < 4; ++j4) {
    float4v v = *(const float4v*)(src + j4 * 4);
#pragma unroll
    for (int i = 0; i < 4; ++i) t[g + j4 * 4 + i][kk] = f2bf(v[i]);
  }
  __syncthreads();
  const int nn = threadIdx.x >> 2, kg = (threadIdx.x & 3) * 16;
  short8 o0, o1;
#pragma unroll
  for (int j = 0; j < 8; ++j) { o0[j] = t[nn][kg + j]; o1[j] = t[nn][kg + 8 + j]; }
  unsigned short* dst = WT + (size_t)(n0 + nn) * 64 + kg;
  *(short8*)dst = o0;
  *(short8*)(dst + 8) = o1;
}

// -------- V slab [2048,64] -> k-tiled VT[bh][k/64][64 d][64 k] --------
__global__ __launch_bounds__(256) void k_tv(const unsigned short* __restrict__ Vb,
                                            unsigned short* __restrict__ VT) {
  __shared__ alignas(16) unsigned short t[64][72];
  const int bh = blockIdx.y, r0 = blockIdx.x * 64;
  const int rr = threadIdx.x & 63, g = (threadIdx.x >> 6) * 16;
  const unsigned short* src = Vb + (size_t)bh * 131072 + (size_t)(r0 + rr) * 64 + g;
  short8 a = *(const short8*)src;
  short8 b = *(const short8*)(src + 8);
#pragma unroll
  for (int j = 0; j < 8; ++j) { t[g + j][rr] = a[j]; t[g + 8 + j][rr] = b[j]; }
  __syncthreads();
  const int d = threadIdx.x >> 2, rg = (threadIdx.x & 3) * 16;
  short8 o0, o1;
#pragma unroll
  for (int j = 0; j < 8; ++j) { o0[j] = t[d][rg + j]; o1[j] = t[d][rg + 8 + j]; }
  unsigned short* dst = VT + (size_t)bh * 131072 + (size_t)(r0 >> 6) * 4096 + d * 64 + rg;
  *(short8*)dst = o0;
  *(short8*)(dst + 8) = o1;
}

// ------- fused QKV GEMM: 128x128 tile, dbuf LDS, T2 XOR swizzle -------
// grid (32,12): 384 blocks, 64 KB LDS -> 2 blocks/CU, all co-resident.
__global__ __launch_bounds__(256) void k_gemmqkv(const unsigned short* __restrict__ A,
                                                 const unsigned short* __restrict__ WT,
                                                 unsigned short* __restrict__ Q,
                                                 unsigned short* __restrict__ K_,
                                                 unsigned short* __restrict__ V_) {
  __shared__ alignas(16) unsigned short As[2][8192];   // [buf][128r x 64k] swizzled
  __shared__ alignas(16) unsigned short Bs[2][8192];
  const int tid = threadIdx.x, w = tid >> 6, l = tid & 63;
  const int lr = l & 15, lg = l >> 4;
  const int m0 = blockIdx.x * 128;
  const int yy = blockIdx.y;
  const int wr = w >> 1, wc = w & 1;
  // staging source: row srow + i*32, column chunk pre-XOR-swizzled (rule 21)
  const int srow = w * 8 + (l >> 3);
  const int scol = (((l & 7) ^ ((l >> 3) & 7)) << 3);
  const unsigned short* ga = A  + (size_t)(m0 + srow) * 1024 + scol;
  const unsigned short* gb = WT + (size_t)(yy * 128 + srow) * 1024 + scol;

#define QKV_STAGE(buf, k0)                                                     \
  {                                                                            \
    _Pragma("unroll")                                                          \
    for (int i = 0; i < 4; ++i) {                                              \
      GLD_LDS16(ga + (size_t)i * 32768 + (k0), &As[buf][(i * 32 + w * 8) * 64]); \
      GLD_LDS16(gb + (size_t)i * 32768 + (k0), &Bs[buf][(i * 32 + w * 8) * 64]); \
    }                                                                          \
  }

  QKV_STAGE(0, 0);
  asm volatile("s_waitcnt vmcnt(0)" ::: "memory");
  __syncthreads();

  f32x4 acc[4][4] = {};
  int cur = 0;
  for (int kt = 0; kt < 16; ++kt) {
    if (kt < 15) QKV_STAGE(cur ^ 1, (kt + 1) * 64);
#pragma unroll
    for (int kk = 0; kk < 2; ++kk) {
      short8 a[4], b[4];
#pragma unroll
      for (int mi = 0; mi < 4; ++mi)
        a[mi] = *(const short8*)&As[cur][(wr * 64 + mi * 16 + lr) * 64 +
                                         (((kk * 4 + lg) ^ (lr & 7)) << 3)];
#pragma unroll
      for (int ni = 0; ni < 4; ++ni)
        b[ni] = *(const short8*)&Bs[cur][(wc * 64 + ni * 16 + lr) * 64 +
                                         (((kk * 4 + lg) ^ (lr & 7)) << 3)];
      __builtin_amdgcn_s_setprio(1);
#pragma unroll
      for (int mi = 0; mi < 4; ++mi)
#pragma unroll
        for (int ni = 0; ni < 4; ++ni)
          acc[mi][ni] = __builtin_amdgcn_mfma_f32_16x16x32_bf16(a[mi], b[ni], acc[mi][ni], 0, 0, 0);
      __builtin_amdgcn_s_setprio(0);
    }
    asm volatile("s_waitcnt vmcnt(0)" ::: "memory");
    __syncthreads();
    cur ^= 1;
  }
  const int which = yy >> 2;
  unsigned short* C = (which == 0) ? Q : (which == 1) ? K_ : V_;
  const int cbase = (yy & 3) * 128 + wc * 64;
#pragma unroll
  for (int mi = 0; mi < 4; ++mi)
#pragma unroll
    for (int ni = 0; ni < 4; ++ni) {
      int row = m0 + wr * 64 + mi * 16 + lg * 4;
      int col = cbase + ni * 16 + lr;
#pragma unroll
      for (int r = 0; r < 4; ++r)
        C[(size_t)(row + r) * 512 + col] = f2bf(acc[mi][ni][r]);
    }
}

// ------- flash attention: 8 waves x 16 q, KBLK=128, LDS dbuf, XCD-mapped -------
__global__ __launch_bounds__(512) void k_attn(const unsigned short* __restrict__ Qb,
                                              const unsigned short* __restrict__ Kb,
                                              const unsigned short* __restrict__ VT,
                                              unsigned short* __restrict__ ctx) {
  __shared__ alignas(16) unsigned short Ks[2][8192];
  __shared__ alignas(16) unsigned short Vs[2][8192];
  __shared__ alignas(16) unsigned short Plds[8][16][128];
  const int tid = threadIdx.x, w = tid >> 6, l = tid & 63;
  const int lr = l & 15, lg = l >> 4;
  const int bid = blockIdx.x;
  const int xcd = bid & 7, j = bid >> 3;
  const int bh = xcd * 2 + (j >> 4);
  const int q0 = (j & 15) * 128;
  const int qrow = q0 + w * 16;
  const unsigned short* Qh  = Qb + (size_t)bh * 131072;
  const unsigned short* Kh  = Kb + (size_t)bh * 131072;
  const unsigned short* VTh = VT + (size_t)bh * 131072;

  short8 qb0 = *(const short8*)&Qh[(size_t)(qrow + lr) * 64 + lg * 8];
  short8 qb1 = *(const short8*)&Qh[(size_t)(qrow + lr) * 64 + 32 + lg * 8];

  const int srow = w * 8 + (l >> 3);
  const int scol = (((l & 7) ^ ((l >> 3) & 7)) << 3);
  const unsigned short* kps = Kh  + (size_t)srow * 64 + scol;
  const unsigned short* vps = VTh + (size_t)srow * 64 + scol;

#define STAGE(buf, it)                                                         \
  {                                                                            \
    _Pragma("unroll")                                                          \
    for (int sub = 0; sub < 2; ++sub) {                                        \
      GLD_LDS16(kps + (size_t)(2 * (it) + sub) * 4096, &Ks[buf][sub * 4096 + w * 512]); \
      GLD_LDS16(vps + (size_t)(2 * (it) + sub) * 4096, &Vs[buf][sub * 4096 + w * 512]); \
    }                                                                          \
  }

  f32x4 O[4] = {};
  float m_i = -1e30f, l_i = 0.f;

  STAGE(0, 0);
  asm volatile("s_waitcnt vmcnt(0)" ::: "memory");
  __syncthreads();

  const int fcol = ((lg ^ (lr & 7)) << 3);
  char* prow = (char*)&Plds[w][lr][0];
  int cur = 0;
#pragma unroll 2
  for (int it = 0; it < 16; ++it) {
    if (it < 15) STAGE(cur ^ 1, it + 1);
    // ---- S^T = K @ Q^T over 128 k ----
    f32x4 s[8] = {};
    __builtin_amdgcn_s_setprio(1);
#pragma unroll
    for (int t = 0; t < 8; ++t) {
      const unsigned short* kRow = &Ks[cur][(t >> 2) * 4096 + ((t & 3) * 16 + lr) * 64];
      short8 ka = *(const short8*)(kRow + fcol);
      short8 kc = *(const short8*)(kRow + (fcol ^ 32));
      s[t] = __builtin_amdgcn_mfma_f32_16x16x32_bf16(ka, qb0, s[t], 0, 0, 0);
      s[t] = __builtin_amdgcn_mfma_f32_16x16x32_bf16(kc, qb1, s[t], 0, 0, 0);
    }
    __builtin_amdgcn_s_setprio(0);
    // ---- V fragments (issued early; latency hidden under softmax) ----
    short8 vf[4][4];
#pragma unroll
    for (int f = 0; f < 4; ++f) {
      const char* vRow0 = (const char*)&Vs[cur][(f * 16 + lr) * 64];
#pragma unroll
      for (int ks = 0; ks < 4; ++ks) {
        int ch = (((ks & 1) * 4 + lg) ^ (lr & 7));
        vf[f][ks] = *(const short8*)(vRow0 + (ks >> 1) * 8192 + ch * 16);
      }
    }
    // ---- online softmax (per-lane q=lr; reduce across 4 lg-lanes) ----
    float tm[8];
#pragma unroll
    for (int t = 0; t < 8; ++t)
      tm[t] = fmaxf(fmaxf(s[t][0], s[t][1]), fmaxf(s[t][2], s[t][3]));
    float tmax = fmaxf(fmaxf(fmaxf(tm[0], tm[1]), fmaxf(tm[2], tm[3])),
                       fmaxf(fmaxf(tm[4], tm[5]), fmaxf(tm[6], tm[7])));
    tmax = fmaxf(tmax, __shfl_xor(tmax, 16));
    tmax = fmaxf(tmax, __shfl_xor(tmax, 32));
    float mnew  = fmaxf(m_i, tmax);
    float alpha = __expf(m_i - mnew);
    float p[8][4];
#pragma unroll
    for (int t = 0; t < 8; ++t)
#pragma unroll
      for (int r = 0; r < 4; ++r) p[t][r] = __expf(s[t][r] - mnew);
    float us[8];
#pragma unroll
    for (int t = 0; t < 8; ++t)
      us[t] = (p[t][0] + p[t][1]) + (p[t][2] + p[t][3]);
    float ls = ((us[0] + us[1]) + (us[2] + us[3])) + ((us[4] + us[5]) + (us[6] + us[7]));
    ls += __shfl_xor(ls, 16);
    ls += __shfl_xor(ls, 32);
    l_i = l_i * alpha + ls;
    m_i = mnew;
#pragma unroll
    for (int f = 0; f < 4; ++f) O[f] *= alpha;
    // ---- P -> swizzled per-wave LDS bounce ----
#pragma unroll
    for (int t = 0; t < 8; ++t) {
      short4v pk;
#pragma unroll
      for (int r = 0; r < 4; ++r) pk[r] = (short)f2bf(p[t][r]);
      int ch = ((2 * t + (lg >> 1)) ^ (lr & 7));
      *(short4v*)(prow + ch * 16 + (lg & 1) * 8) = pk;
    }
    asm volatile("s_waitcnt lgkmcnt(0)" ::: "memory");
    __builtin_amdgcn_sched_barrier(0);
    short8 pb[4];
#pragma unroll
    for (int ks = 0; ks < 4; ++ks)
      pb[ks] = *(const short8*)(prow + (((ks * 4 + lg) ^ (lr & 7)) << 4));
    // ---- O^T += V @ P ----
    __builtin_amdgcn_s_setprio(1);
#pragma unroll
    for (int ks = 0; ks < 4; ++ks)
#pragma unroll
      for (int f = 0; f < 4; ++f)
        O[f] = __builtin_amdgcn_mfma_f32_16x16x32_bf16(vf[f][ks], pb[ks], O[f], 0, 0, 0);
    __builtin_amdgcn_s_setprio(0);
    if (it < 15) {
      asm volatile("s_waitcnt vmcnt(0)" ::: "memory");
      __syncthreads();
    }
    cur ^= 1;
  }
  const float scale = 0.125f / l_i;
  unsigned short* base = ctx + (size_t)(bh * 2048 + qrow + lr) * 64;
#pragma unroll
  for (int f = 0; f < 4; ++f) {
    short4v o;
#pragma unroll
    for (int r = 0; r < 4; ++r) o[r] = (short)f2bf(O[f][r] * scale);
    *(short4v*)(base + f * 16 + lg * 4) = o;
  }
}

// ------- out projection: OUT[32768,1024] f32 = ctx @ WoT^T + bo -------
__global__ __launch_bounds__(256) void k_gemmo(const unsigned short* __restrict__ A,
                                               const unsigned short* __restrict__ BT,
                                               const float* __restrict__ bias,
                                               float* __restrict__ C) {
  __shared__ alignas(16) unsigned short As[128 * 64];
  __shared__ alignas(16) unsigned short Bs[128 * 64];
  const int tid = threadIdx.x, w = tid >> 6, l = tid & 63;
  const int lr = l & 15, lg = l >> 4;
  const int m0 = blockIdx.x * 128, n0 = blockIdx.y * 128;
  const int wr = w >> 1, wc = w & 1;
  const int srow = w * 8 + (l >> 3);
  const int scol = (l & 7) * 8;
  const unsigned short* ga = A  + (size_t)(m0 + srow) * 64 + scol;
  const unsigned short* gb = BT + (size_t)(n0 + srow) * 64 + scol;
#pragma unroll
  for (int i = 0; i < 4; ++i) {
    GLD_LDS16(ga + (size_t)i * 2048, As + (i * 32 + w * 8) * 64);
    GLD_LDS16(gb + (size_t)i * 2048, Bs + (i * 32 + w * 8) * 64);
  }
  asm volatile("s_waitcnt vmcnt(0)" ::: "memory");
  __syncthreads();
  f32x4 acc[4][4] = {};
#pragma unroll
  for (int kk = 0; kk < 2; ++kk) {
    short8 a[4], b[4];
#pragma unroll
    for (int mi = 0; mi < 4; ++mi)
      a[mi] = *(const short8*)&As[(wr * 64 + mi * 16 + lr) * 64 + kk * 32 + lg * 8];
#pragma unroll
    for (int ni = 0; ni < 4; ++ni)
      b[ni] = *(const short8*)&Bs[(wc * 64 + ni * 16 + lr) * 64 + kk * 32 + lg * 8];
#pragma unroll
    for (int mi = 0; mi < 4; ++mi)
#pragma unroll
      for (int ni = 0; ni < 4; ++ni)
        acc[mi][ni] = __builtin_amdgcn_mfma_f32_16x16x32_bf16(a[mi], b[ni], acc[mi][ni], 0, 0, 0);
  }
  float bv[4];
#pragma unroll
  for (int ni = 0; ni < 4; ++ni) bv[ni] = bias[n0 + wc * 64 + ni * 16 + lr];
#pragma unroll
  for (int mi = 0; mi < 4; ++mi)
#pragma unroll
    for (int ni = 0; ni < 4; ++ni) {
      int row = m0 + wr * 64 + mi * 16 + lg * 4;
      int col = n0 + wc * 64 + ni * 16 + lr;
#pragma unroll
      for (int r = 0; r < 4; ++r)
        C[(size_t)(row + r) * 1024 + col] = acc[mi][ni][r] + bv[ni];
    }
}

extern "C" void kernel_launch(void* const* d_in, const int* in_sizes, int n_in,
                              void* d_out, int out_size, void* d_ws, size_t ws_size,
                              hipStream_t stream) {
  const float* X  = (const float*)d_in[0];
  const float* Wq = (const float*)d_in[1];
  const float* Wk = (const float*)d_in[2];
  const float* Wv = (const float*)d_in[3];
  const float* Wo = (const float*)d_in[4];
  const float* bo = (const float*)d_in[5];
  float* out = (float*)d_out;

  char* ws = (char*)d_ws;
  unsigned short* Xb    = (unsigned short*)ws; ws += 8388608;
  unsigned short* WqkvT = (unsigned short*)ws; ws += 3145728;
  unsigned short* WoT   = (unsigned short*)ws; ws += 131072;
  unsigned short* Qb    = (unsigned short*)ws; ws += 4194304;
  unsigned short* Kb    = (unsigned short*)ws; ws += 4194304;
  unsigned short* Vb    = (unsigned short*)ws; ws += 4194304;
  unsigned short* VT    = (unsigned short*)ws; ws += 4194304;
  unsigned short* Cx    = (unsigned short*)ws; ws += 4194304;

  k_cvt<<<4096, 256, 0, stream>>>(X, Xb, 1048576);
  k_twt3<<<dim3(16, 8, 3), 256, 0, stream>>>(Wq, Wk, Wv, WqkvT);
  k_twtO<<<dim3(1, 16), 256, 0, stream>>>(Wo, WoT);

  k_gemmqkv<<<dim3(32, 12), 256, 0, stream>>>(Xb, WqkvT, Qb, Kb, Vb);

  k_tv<<<dim3(32, 16), 256, 0, stream>>>(Vb, VT);
  k_attn<<<256, 512, 0, stream>>>(Qb, Kb, VT, Cx);
  k_gemmo<<<dim3(256, 8), 256, 0, stream>>>(Cx, WoT, bo, out);
}